// Round 3
// baseline (1179.011 us; speedup 1.0000x reference)
//
#include <hip/hip_runtime.h>

#define CGN    4096
#define NBLK   256
#define NTHR   1024
#define NW     (NTHR / 64)       // 16 waves/block
#define RPB    (CGN / NBLK)      // 16 rows per block (1 per wave)
#define MAX_IT 20
#define TOLF   1e-8f

// Module-scope scratch: zero-initialized at load, fully rewritten before use
// on every call (deterministic). Avoids any dependence on d_ws size.
__device__ float    g_Ap[CGN];
__device__ float    g_r[CGN];
__device__ float    g_p0[CGN];
__device__ float    g_p1[CGN];
__device__ float    g_part_pAp[NBLK];
__device__ float    g_part_rs[NBLK];
__device__ unsigned g_bar;   // monotonic barrier counter; stays multiple of NBLK between calls

__device__ __forceinline__ float wave_reduce(float v) {
    #pragma unroll
    for (int off = 32; off > 0; off >>= 1)
        v += __shfl_down(v, off, 64);
    return v;  // lane 0 holds the sum
}

// Device-scope sense-free barrier (monotonic ticket counter, wrap-safe compare).
// Release/acquire via device-scope fences: correct across non-coherent per-XCD L2s.
__device__ __forceinline__ void grid_barrier() {
    __syncthreads();
    if (threadIdx.x == 0) {
        __threadfence();  // release: publish this block's global writes
        unsigned ticket = __hip_atomic_fetch_add(&g_bar, 1u, __ATOMIC_ACQ_REL,
                                                 __HIP_MEMORY_SCOPE_AGENT);
        unsigned target = (ticket & ~(unsigned)(NBLK - 1)) + NBLK;
        while ((int)(__hip_atomic_load(&g_bar, __ATOMIC_ACQUIRE,
                                       __HIP_MEMORY_SCOPE_AGENT) - target) < 0) {
            __builtin_amdgcn_s_sleep(2);
        }
        __threadfence();  // acquire: invalidate stale cached lines
    }
    __syncthreads();
}

__global__ __launch_bounds__(NTHR, 1) void pcg_kernel(
    const float* __restrict__ A, const float* __restrict__ b,
    float* __restrict__ x)
{
    __shared__ float p_lds[CGN];   // full p vector, 16 KiB
    __shared__ float red[NW];
    __shared__ float dotw[NW];

    const int tid  = threadIdx.x;
    const int blk  = blockIdx.x;
    const int lane = tid & 63;
    const int wv   = tid >> 6;
    const int t    = blk * NTHR + tid;   // blocks 0-3 own the vector elements

    // ---- init: r = b, x = 0, block partials of b.b ----
    float sq = 0.f;
    if (t < CGN) {
        float bv = b[t];
        g_r[t] = bv;
        x[t]   = 0.f;
        sq = bv * bv;
    }
    {
        float s = wave_reduce(sq);
        if (lane == 0) red[wv] = s;
        __syncthreads();
        if (tid == 0) {
            float a = 0.f;
            #pragma unroll
            for (int i = 0; i < NW; ++i) a += red[i];
            g_part_rs[blk] = a;
        }
    }
    grid_barrier();

    float rs_old = 0.f;
    for (int k = 0; k < MAX_IT; ++k) {
        // ---- all-reduce part_rs -> rs (identical order in every block => uniform) ----
        float v = (tid < NBLK) ? g_part_rs[tid] : 0.f;
        v = wave_reduce(v);
        if (lane == 0) red[wv] = v;
        __syncthreads();
        float rs = 0.f;
        #pragma unroll
        for (int i = 0; i < NW; ++i) rs += red[i];
        __syncthreads();

        if (!(rs >= TOLF * TOLF)) break;   // uniform across grid

        float bk = (k == 0) ? 0.f : rs / rs_old;
        rs_old = rs;

        const float* pprev = (k & 1) ? g_p0 : g_p1;
        float*       pcur  = (k & 1) ? g_p1 : g_p0;

        // ---- p = r + bk*p_prev: full vector into LDS (redundant per block),
        //      own float4 slice to global ----
        {
            int i4 = tid;                              // one float4 per thread
            float4 rv = ((const float4*)g_r)[i4];
            float4 pv = ((const float4*)pprev)[i4];
            float4 pc;
            pc.x = rv.x + bk * pv.x;
            pc.y = rv.y + bk * pv.y;
            pc.z = rv.z + bk * pv.z;
            pc.w = rv.w + bk * pv.w;
            *(float4*)&p_lds[i4 * 4] = pc;
            if ((i4 >> 2) == blk) ((float4*)pcur)[i4] = pc;  // own 16 elements
        }
        __syncthreads();

        // ---- matvec: wave wv computes row blk*16 + wv ----
        int row = blk * RPB + wv;
        const float4* Arow = (const float4*)(A + (size_t)row * CGN);
        float acc = 0.f;
        #pragma unroll
        for (int j = 0; j < 16; ++j) {
            int c4 = j * 64 + lane;
            float4 a4 = Arow[c4];
            float4 p4 = *(const float4*)&p_lds[c4 * 4];
            acc += a4.x * p4.x + a4.y * p4.y + a4.z * p4.z + a4.w * p4.w;
        }
        acc = wave_reduce(acc);
        if (lane == 0) {
            g_Ap[row] = acc;
            dotw[wv]  = p_lds[row] * acc;
        }
        __syncthreads();
        if (tid == 0) {
            float a = 0.f;
            #pragma unroll
            for (int i = 0; i < NW; ++i) a += dotw[i];
            g_part_pAp[blk] = a;
        }
        grid_barrier();   // S1: Ap, pcur, part_pAp published

        // ---- all-reduce part_pAp -> pAp; ak; update x, r; partials of r1.r1 ----
        float u = (tid < NBLK) ? g_part_pAp[tid] : 0.f;
        u = wave_reduce(u);
        if (lane == 0) red[wv] = u;
        __syncthreads();
        float pAp = 0.f;
        #pragma unroll
        for (int i = 0; i < NW; ++i) pAp += red[i];
        __syncthreads();

        float ak = rs / pAp;
        float sq2 = 0.f;
        if (t < CGN) {
            float pv = pcur[t];
            x[t] += ak * pv;
            float rn = g_r[t] - ak * g_Ap[t];
            g_r[t] = rn;
            sq2 = rn * rn;
        }
        float s2 = wave_reduce(sq2);
        if (lane == 0) red[wv] = s2;
        __syncthreads();
        if (tid == 0) {
            float a = 0.f;
            #pragma unroll
            for (int i = 0; i < NW; ++i) a += red[i];
            g_part_rs[blk] = a;
        }
        grid_barrier();   // S2: r, x, part_rs published
    }
}

extern "C" void kernel_launch(void* const* d_in, const int* in_sizes, int n_in,
                              void* d_out, int out_size, void* d_ws, size_t ws_size,
                              hipStream_t stream) {
    const float* A = (const float*)d_in[0];
    const float* b = (const float*)d_in[1];
    float* x = (float*)d_out;
    pcg_kernel<<<dim3(NBLK), dim3(NTHR), 0, stream>>>(A, b, x);
}

// Round 6
// 576.139 us; speedup vs baseline: 2.0464x; 2.0464x over previous
//
#include <hip/hip_runtime.h>

#define CGN    4096
#define NBLK   256
#define NTHR   1024
#define NW     (NTHR / 64)       // 16 waves/block
#define RPB    (CGN / NBLK)      // 16 rows/elements owned per block
#define MAX_IT 20
#define TOLF   1e-8f

// Module-scope scratch (.bss). Fully rewritten each call => deterministic.
__device__ float    g_r[CGN];
__device__ float    g_p0[CGN];
__device__ float    g_p1[CGN];
__device__ float    g_part_pAp[NBLK];
__device__ float    g_part_rs[NBLK];
__device__ unsigned g_bar;   // monotonic ticket counter (multiple of NBLK between calls)

// Coherence-point (L3) accesses for cross-block data. RELAXED => no cache
// maintenance instructions (no buffer_inv / buffer_wbl2); AGENT scope =>
// sc-flagged, bypassing stale L1/L2 lines. A stays warm in L2 across iters.
#define AL(p)   __hip_atomic_load((p), __ATOMIC_RELAXED, __HIP_MEMORY_SCOPE_AGENT)
#define AS(p,v) __hip_atomic_store((p), (v), __ATOMIC_RELAXED, __HIP_MEMORY_SCOPE_AGENT)

__device__ __forceinline__ float wave_reduce(float v) {
    #pragma unroll
    for (int off = 32; off > 0; off >>= 1)
        v += __shfl_down(v, off, 64);
    return v;  // lane 0 holds the sum
}

// Fence-free grid barrier. The __syncthreads() drains vmcnt before s_barrier,
// so every sc-flagged store has reached the coherence point before the
// arrival add. Consumers read via sc-flagged loads => no staleness.
__device__ __forceinline__ void grid_barrier() {
    __syncthreads();
    if (threadIdx.x == 0) {
        unsigned ticket = __hip_atomic_fetch_add(&g_bar, 1u, __ATOMIC_RELAXED,
                                                 __HIP_MEMORY_SCOPE_AGENT);
        unsigned target = (ticket & ~(unsigned)(NBLK - 1)) + NBLK;
        while ((int)(__hip_atomic_load(&g_bar, __ATOMIC_RELAXED,
                                       __HIP_MEMORY_SCOPE_AGENT) - target) < 0) {
            __builtin_amdgcn_s_sleep(8);
        }
    }
    __syncthreads();
}

__global__ __launch_bounds__(NTHR, 1) void pcg_kernel(
    const float* __restrict__ A, const float* __restrict__ b,
    float* __restrict__ x)
{
    __shared__ float p_lds[CGN];   // full p vector, 16 KiB (rebuilt per block)
    __shared__ float ap_lds[NW];   // Ap for own rows (row = blk*RPB + wv)
    __shared__ float dotw[NW];
    __shared__ float red[NW];

    const int tid  = threadIdx.x;
    const int blk  = blockIdx.x;
    const int lane = tid & 63;
    const int wv   = tid >> 6;

    // ---- init: own RPB elements: r = b, x = 0, partial b.b ----
    if (wv == 0) {                        // full wave active: no divergent shfl
        float sq = 0.f;
        if (lane < RPB) {
            int e = blk * RPB + lane;
            float bv = b[e];
            AS(&g_r[e], bv);
            x[e] = 0.f;
            sq = bv * bv;
        }
        sq = wave_reduce(sq);
        if (lane == 0) AS(&g_part_rs[blk], sq);
    }
    grid_barrier();

    float rs_old = 0.f;
    for (int k = 0; k < MAX_IT; ++k) {
        // ---- all-reduce part_rs -> rs (identical order in every block) ----
        float v = (tid < NBLK) ? AL(&g_part_rs[tid]) : 0.f;
        v = wave_reduce(v);
        if (lane == 0) red[wv] = v;
        __syncthreads();
        float rs = 0.f;
        #pragma unroll
        for (int i = 0; i < NW; ++i) rs += red[i];
        __syncthreads();

        if (!(rs >= TOLF * TOLF)) break;   // uniform across grid

        float bk = (k == 0) ? 0.f : rs / rs_old;
        rs_old = rs;

        float* pprev = (k & 1) ? g_p0 : g_p1;
        float* pcur  = (k & 1) ? g_p1 : g_p0;

        // ---- p = r + bk*p_prev: full vector into LDS (redundant per block),
        //      own RPB elements published to global ----
        {
            int base = tid * 4;            // one float4-slot per thread
            float p0 = AL(&g_r[base + 0]) + bk * AL(&pprev[base + 0]);
            float p1 = AL(&g_r[base + 1]) + bk * AL(&pprev[base + 1]);
            float p2 = AL(&g_r[base + 2]) + bk * AL(&pprev[base + 2]);
            float p3 = AL(&g_r[base + 3]) + bk * AL(&pprev[base + 3]);
            p_lds[base + 0] = p0;
            p_lds[base + 1] = p1;
            p_lds[base + 2] = p2;
            p_lds[base + 3] = p3;
            if ((tid >> 2) == blk) {       // 4 threads own the block's 16 elems
                AS(&pcur[base + 0], p0);
                AS(&pcur[base + 1], p1);
                AS(&pcur[base + 2], p2);
                AS(&pcur[base + 3], p3);
            }
        }
        __syncthreads();

        // ---- matvec: wave wv computes row blk*RPB + wv (A via plain cached loads) ----
        const float4* Arow = (const float4*)(A + (size_t)(blk * RPB + wv) * CGN);
        float acc = 0.f;
        #pragma unroll
        for (int j = 0; j < 16; ++j) {
            int c4 = j * 64 + lane;
            float4 a4 = Arow[c4];
            float4 p4 = *(const float4*)&p_lds[c4 * 4];
            acc += a4.x * p4.x + a4.y * p4.y + a4.z * p4.z + a4.w * p4.w;
        }
        acc = wave_reduce(acc);
        if (lane == 0) {
            ap_lds[wv] = acc;
            dotw[wv]   = p_lds[blk * RPB + wv] * acc;
        }
        __syncthreads();
        if (tid == 0) {
            float a = 0.f;
            #pragma unroll
            for (int i = 0; i < NW; ++i) a += dotw[i];
            AS(&g_part_pAp[blk], a);
        }
        grid_barrier();   // S1: pcur, part_pAp at coherence point

        // ---- all-reduce part_pAp -> pAp; ak; local update of own r, x ----
        float u = (tid < NBLK) ? AL(&g_part_pAp[tid]) : 0.f;
        u = wave_reduce(u);
        if (lane == 0) red[wv] = u;
        __syncthreads();
        float pAp = 0.f;
        #pragma unroll
        for (int i = 0; i < NW; ++i) pAp += red[i];
        __syncthreads();

        float ak = rs / pAp;
        if (wv == 0) {                     // full wave active: no divergent shfl
            float sq = 0.f;
            if (lane < RPB) {
                int e = blk * RPB + lane;
                float pv  = p_lds[e];
                float Apv = ap_lds[lane];
                float rn  = AL(&g_r[e]) - ak * Apv;
                AS(&g_r[e], rn);
                x[e] += ak * pv;
                sq = rn * rn;
            }
            sq = wave_reduce(sq);
            if (lane == 0) AS(&g_part_rs[blk], sq);
        }
        grid_barrier();   // S2: r, part_rs at coherence point
    }
}

extern "C" void kernel_launch(void* const* d_in, const int* in_sizes, int n_in,
                              void* d_out, int out_size, void* d_ws, size_t ws_size,
                              hipStream_t stream) {
    const float* A = (const float*)d_in[0];
    const float* b = (const float*)d_in[1];
    float* x = (float*)d_out;
    pcg_kernel<<<dim3(NBLK), dim3(NTHR), 0, stream>>>(A, b, x);
}

// Round 7
// 198.511 us; speedup vs baseline: 5.9393x; 2.9023x over previous
//
#include <hip/hip_runtime.h>

#define CGN    4096
#define NBLK   256
#define NTHR   1024
#define NW     (NTHR / 64)       // 16 waves/block
#define RPB    (CGN / NBLK)      // 16 rows/elements owned per block
#define MAX_IT 20
#define TOLF   1e-8f

// Module-scope scratch (.bss). Deterministic: fully rewritten or monotonic.
__device__ float    g_r[CGN];
__device__ float    g_p0[CGN];
__device__ float    g_p1[CGN];
__device__ float    g_part_pAp[NBLK];
__device__ float    g_part_rs[NBLK];
__device__ unsigned g_flags[NBLK];  // per-block arrival epochs (monotonic)
__device__ unsigned g_release;      // block-0-owned release epoch (monotonic)

// Coherence-point (L3) accesses for cross-block data. RELAXED => no cache
// maintenance instructions; AGENT scope => sc-flagged, bypass stale L1/L2.
#define AL(p)   __hip_atomic_load((p), __ATOMIC_RELAXED, __HIP_MEMORY_SCOPE_AGENT)
#define AS(p,v) __hip_atomic_store((p), (v), __ATOMIC_RELAXED, __HIP_MEMORY_SCOPE_AGENT)

__device__ __forceinline__ float wave_reduce(float v) {
    #pragma unroll
    for (int off = 32; off > 0; off >>= 1)
        v += __shfl_down(v, off, 64);
    return v;  // lane 0 holds the sum
}

// Hierarchical flag barrier: arrival = plain sc-store (no RMW serialization).
// Block 0 polls all flags, then publishes a single release word; other blocks
// poll only the release word. __syncthreads() before arrival drains each
// wave's vmcnt, so all data stores reached the coherence point first.
__device__ __forceinline__ void grid_barrier(int blk, int tid, unsigned target) {
    __syncthreads();
    if (tid == 0) AS(&g_flags[blk], target);
    if (blk == 0) {
        if (tid < NBLK) {
            while ((int)(AL(&g_flags[tid]) - target) < 0)
                __builtin_amdgcn_s_sleep(2);
        }
        __syncthreads();                 // all 256 flags confirmed
        if (tid == 0) AS(&g_release, target);
    } else {
        if (tid == 0) {
            while ((int)(AL(&g_release) - target) < 0)
                __builtin_amdgcn_s_sleep(2);
        }
    }
    __syncthreads();
}

__global__ __launch_bounds__(NTHR, 1) void pcg_kernel(
    const float* __restrict__ A, const float* __restrict__ b,
    float* __restrict__ x)
{
    __shared__ float p_lds[CGN];   // full p vector, 16 KiB (rebuilt per block)
    __shared__ float ap_lds[NW];   // Ap for own rows (row = blk*RPB + wv)
    __shared__ float red[NW];

    const int tid  = threadIdx.x;
    const int blk  = blockIdx.x;
    const int lane = tid & 63;
    const int wv   = tid >> 6;

    const unsigned base = AL(&g_flags[blk]);  // all flags equal between calls
    unsigned bcount = 0;

    // ---- load own A row-slice into registers ONCE (64 VGPRs/thread) ----
    const float4* Arow = (const float4*)(A + (size_t)(blk * RPB + wv) * CGN);
    float4 arow[16];
    #pragma unroll
    for (int j = 0; j < 16; ++j) arow[j] = Arow[j * 64 + lane];

    // ---- init: own RPB elements: r = b, x = 0, partial b.b ----
    float r_own = 0.f, x_own = 0.f;      // live in wave 0, lanes < RPB
    if (wv == 0) {
        float sq = 0.f;
        if (lane < RPB) {
            int e = blk * RPB + lane;
            r_own = b[e];
            AS(&g_r[e], r_own);
            sq = r_own * r_own;
        }
        sq = wave_reduce(sq);
        if (lane == 0) AS(&g_part_rs[blk], sq);
    }
    grid_barrier(blk, tid, base + (++bcount));

    float rs_old = 0.f;
    for (int k = 0; k < MAX_IT; ++k) {
        // ---- all-reduce part_rs -> rs (identical order in every block) ----
        float v = (tid < NBLK) ? AL(&g_part_rs[tid]) : 0.f;
        v = wave_reduce(v);
        if (lane == 0) red[wv] = v;
        __syncthreads();
        float rs = 0.f;
        #pragma unroll
        for (int i = 0; i < NW; ++i) rs += red[i];
        __syncthreads();

        if (!(rs >= TOLF * TOLF)) break;   // uniform across grid

        float bk = (k == 0) ? 0.f : rs / rs_old;
        rs_old = rs;

        float* pprev = (k & 1) ? g_p0 : g_p1;
        float* pcur  = (k & 1) ? g_p1 : g_p0;

        // ---- p = r + bk*p_prev: full vector into LDS (redundant per block),
        //      own RPB elements published to global ----
        {
            int bidx = tid * 4;            // one float4-slot per thread
            float p0 = AL(&g_r[bidx + 0]) + bk * AL(&pprev[bidx + 0]);
            float p1 = AL(&g_r[bidx + 1]) + bk * AL(&pprev[bidx + 1]);
            float p2 = AL(&g_r[bidx + 2]) + bk * AL(&pprev[bidx + 2]);
            float p3 = AL(&g_r[bidx + 3]) + bk * AL(&pprev[bidx + 3]);
            p_lds[bidx + 0] = p0;
            p_lds[bidx + 1] = p1;
            p_lds[bidx + 2] = p2;
            p_lds[bidx + 3] = p3;
            if ((tid >> 2) == blk) {       // 4 threads own the block's 16 elems
                AS(&pcur[bidx + 0], p0);
                AS(&pcur[bidx + 1], p1);
                AS(&pcur[bidx + 2], p2);
                AS(&pcur[bidx + 3], p3);
            }
        }
        __syncthreads();

        // ---- matvec from REGISTERS: wave wv computes row blk*RPB + wv ----
        float acc = 0.f;
        #pragma unroll
        for (int j = 0; j < 16; ++j) {
            float4 p4 = *(const float4*)&p_lds[(j * 64 + lane) * 4];
            acc += arow[j].x * p4.x + arow[j].y * p4.y
                 + arow[j].z * p4.z + arow[j].w * p4.w;
        }
        acc = wave_reduce(acc);
        if (lane == 0) ap_lds[wv] = acc;
        __syncthreads();

        // ---- own partial of p.Ap (wave 0) ----
        if (wv == 0) {
            float d = 0.f;
            if (lane < RPB) d = p_lds[blk * RPB + lane] * ap_lds[lane];
            d = wave_reduce(d);
            if (lane == 0) AS(&g_part_pAp[blk], d);
        }
        grid_barrier(blk, tid, base + (++bcount));   // S1

        // ---- all-reduce part_pAp -> pAp; ak; local update of own r, x ----
        float u = (tid < NBLK) ? AL(&g_part_pAp[tid]) : 0.f;
        u = wave_reduce(u);
        if (lane == 0) red[wv] = u;
        __syncthreads();
        float pAp = 0.f;
        #pragma unroll
        for (int i = 0; i < NW; ++i) pAp += red[i];
        __syncthreads();

        float ak = rs / pAp;
        if (wv == 0) {
            float sq = 0.f;
            if (lane < RPB) {
                int e = blk * RPB + lane;
                x_own += ak * p_lds[e];
                r_own -= ak * ap_lds[lane];
                AS(&g_r[e], r_own);
                sq = r_own * r_own;
            }
            sq = wave_reduce(sq);
            if (lane == 0) AS(&g_part_rs[blk], sq);
        }
        grid_barrier(blk, tid, base + (++bcount));   // S2
    }

    // ---- write own x elements once ----
    if (wv == 0 && lane < RPB) x[blk * RPB + lane] = x_own;
}

extern "C" void kernel_launch(void* const* d_in, const int* in_sizes, int n_in,
                              void* d_out, int out_size, void* d_ws, size_t ws_size,
                              hipStream_t stream) {
    const float* A = (const float*)d_in[0];
    const float* b = (const float*)d_in[1];
    float* x = (float*)d_out;
    pcg_kernel<<<dim3(NBLK), dim3(NTHR), 0, stream>>>(A, b, x);
}